// Round 4
// baseline (367.425 us; speedup 1.0000x reference)
//
#include <hip/hip_runtime.h>
#include <hip/hip_bf16.h>
#include <stdint.h>

typedef short short8 __attribute__((ext_vector_type(8)));
typedef float f32x4 __attribute__((ext_vector_type(4)));

#define PXS 40     // padded LDS row stride (elements) — balanced bank-quad spread

__device__ __forceinline__ short f2bf(float f) {
    __hip_bfloat16 h = __float2bfloat16(f);
    return __builtin_bit_cast(short, h);
}

// ---- prep 1a: K2(ci,co) = sum_p kernel[p,ci,co]^2  (256 blocks) ------------
__global__ void prep_k2(const float* __restrict__ kern, float* __restrict__ K2)
{
    const int ci = blockIdx.x, co = threadIdx.x;
    float acc = 0.f;
#pragma unroll
    for (int p = 0; p < 9; ++p) {
        float w = kern[(p * 256 + ci) * 256 + co];
        acc += w * w;
    }
    K2[ci * 256 + co] = acc;
}

// ---- prep 1b: demod(b,co) = 1/sqrt( sum_ci style^2 * K2 + eps ) ------------
__global__ void prep_demod(const float* __restrict__ style,
                           const float* __restrict__ K2,
                           float* __restrict__ demod)
{
    const int b = blockIdx.x, co = threadIdx.x;
    __shared__ float s2[256];
    float s = style[b * 256 + co];
    s2[co] = s * s;
    __syncthreads();
    float acc = 0.f;
#pragma unroll 8
    for (int ci = 0; ci < 256; ++ci)
        acc += s2[ci] * K2[ci * 256 + co];
    demod[b * 256 + co] = 1.0f / sqrtf(acc + 1e-7f);
}

// ---- prep 2: fragment-major bf16 weights ----------------------------------
// KF chunk layout: [(st = sl*3+tp)][jt][lane] of short8 (16 B per lane).
// One wave's MFMA B-fragment = one contiguous 1024 B chunk. In v5 these
// chunks are DMA'd into LDS (global_load_lds writes base + lane*16 linearly,
// which IS this layout) and ds_read back wave-contiguous (conflict-free).
__global__ void prep_kf(const float* __restrict__ kern,
                        __hip_bfloat16* __restrict__ kf)
{
    const int st = blockIdx.x;                 // 0..71
    const int sl = st / 3, tp = st - sl * 3;
    const int dh = sl >> 3, cc = sl & 7;
    const int p  = dh * 3 + tp;
    const int t    = threadIdx.x;
    const int lane = t & 63, jt2 = t >> 6;
    const int l15  = lane & 15, lk = lane >> 4;
    const int cib  = cc * 32 + lk * 8;
#pragma unroll
    for (int jj = 0; jj < 4; ++jj) {
        const int jt = jj * 4 + jt2;
        const int co = jt * 16 + l15;
        short8 v;
#pragma unroll
        for (int e = 0; e < 8; ++e)
            v[e] = f2bf(kern[(size_t)(p * 256 + cib + e) * 256 + co]);
        *(short8*)(kf + ((size_t)(st * 16 + jt) * 64 + lane) * 8) = v;
    }
}

// ---- main: implicit-GEMM conv, f32 in / f32 out, bf16 MFMA core ------------
// One block = one (b,h) row (M=128 pixels) x 128 couts.
// v5 changes vs v4 (post-mortem: fence HELD — VGPR 100, 3 live operand sets —
// yet time flat at ~199us across v2..v4. Per-wave register ILP is refuted as
// the lever; real limiter is per-slice kf re-fetch from L1/L2 with shallow
// per-wave MLP: 48 KB of B-fragment requests per block-slice, ~2.4 GB
// aggregate L2 traffic, ~16 outstanding loads/wave max):
//  * kf -> LDS via __builtin_amdgcn_global_load_lds width=16 (m97 pattern):
//    one 24 KB DMA per block-slice (half the request traffic), zero VGPR
//    cost, deep async queue. Double-buffered; issued for slice s+1 BEFORE
//    slice s's MFMAs; the end-of-slice __syncthreads drain completes it
//    (race-free by construction, latency hidden under ~600cyc of compute).
//  * B ds_read is wave-contiguous 1 KB (fragment-major == DMA linear dest).
//  * x reg-prefetch issued BEFORE the DMAs: FIFO vmcnt => waiting for x is
//    vmcnt(6), never forces the DMA drain early.
//  * reverted: sched fence, (256,2) bound, nontemporal stores (those grew
//    WRITE_SIZE 134->178 MB by breaking L2 write merging).
__global__ __launch_bounds__(256) void conv_mfma(
    const float* __restrict__ x,
    const __hip_bfloat16* __restrict__ kf,
    const float* __restrict__ style,
    const float* __restrict__ demod,
    float* __restrict__ out)
{
    __shared__ __align__(16) __hip_bfloat16 Xs[2][130 * PXS];   // 20.8 KB
    __shared__ __align__(16) __hip_bfloat16 KfB[2][24 * 512];   // 48 KB
    __shared__ float Ss[256];
    __shared__ float Ds[128];

    const int t    = threadIdx.x;
    const int bid  = blockIdx.x;
    const int L    = ((bid & 7) << 8) | (bid >> 3);   // XCD-contiguous work id
    const int n0   = (L & 1) << 7;                    // cout tile: 0 or 128
    const int bh   = L >> 1;                          // 0..1023
    const int b    = bh >> 7, h = bh & 127;
    const int wave = t >> 6, lane = t & 63;
    const int wr   = (wave >> 1) << 6;          // wave row base
    const int wc   = (wave & 1) << 6;           // wave col base
    const int wjl  = (wave & 1) << 2;           // local j-tile base in KfB
    const int l15  = lane & 15, lk = lane >> 4;
    const int mA   = t >> 2;                    // staging row 0..63
    const int koff = (t & 3) << 3;              // staging k offset (8 elems)
    const int jb0  = (L & 1) << 3;              // global j-tile base (n0 half)

    if (t < 128) {
        ((float2*)Ss)[t] = ((const float2*)(style + b * 256))[t];
        Ds[t] = demod[b * 256 + n0 + t];
    }
    if (t < 32) {                               // halo rows, never re-written
        const __hip_bfloat16 z = __float2bfloat16(0.f);
        Xs[0][t] = z; Xs[0][129 * PXS + t] = z;
        Xs[1][t] = z; Xs[1][129 * PXS + t] = z;
    }

    f32x4 acc[4][4] = {};

    const int slo = (h == 0)   ? 8  : 0;        // valid slices are contiguous
    const int shi = (h == 127) ? 16 : 24;

    // Wave `wave` DMAs 6 of the 24 1-KB chunks of slice s into KfB[buf].
    // LDS dest is wave-uniform; HW adds lane*16. Global src is per-lane.
    auto stage_kf = [&](int s, int buf) {
#pragma unroll
        for (int k = 0; k < 6; ++k) {
            const int c = (k << 2) + wave;      // 0..23 = tp*8 + jl
            const __hip_bfloat16* src =
                kf + ((size_t)(s * 48 + ((c >> 3) << 4) + jb0 + (c & 7)) * 64
                      + lane) * 8;
            __builtin_amdgcn_global_load_lds(
                (const __attribute__((address_space(1))) void*)src,
                (__attribute__((address_space(3))) void*)&KfB[buf][c * 512],
                16, 0, 0);
        }
    };

    __syncthreads();                            // Ss ready for staging

    // ---- prologue: stage slice slo (kf DMA + x) into buffer 0 ----
    stage_kf(slo, 0);
    {
        const int h2  = h + (slo >> 3) - 1;
        const int ci0 = (slo & 7) << 5;
        const size_t rowbase = (size_t)(b * 128 + h2) * 128;
        const float* ga = x + (rowbase + mA)      * 256 + ci0 + koff;
        const float* gb = x + (rowbase + mA + 64) * 256 + ci0 + koff;
        float4 xa0 = *(const float4*)ga, xa1 = *(const float4*)(ga + 4);
        float4 xb0 = *(const float4*)gb, xb1 = *(const float4*)(gb + 4);
        float4 s0  = *(const float4*)&Ss[ci0 + koff];
        float4 s1  = *(const float4*)&Ss[ci0 + koff + 4];
        short8 ma, mb;
#pragma unroll
        for (int jj = 0; jj < 4; ++jj) {
            ma[jj]     = f2bf((&xa0.x)[jj] * (&s0.x)[jj]);
            ma[jj + 4] = f2bf((&xa1.x)[jj] * (&s1.x)[jj]);
            mb[jj]     = f2bf((&xb0.x)[jj] * (&s0.x)[jj]);
            mb[jj + 4] = f2bf((&xb1.x)[jj] * (&s1.x)[jj]);
        }
        *(short8*)&Xs[0][(mA + 1)  * PXS + koff] = ma;
        *(short8*)&Xs[0][(mA + 65) * PXS + koff] = mb;
    }
    __syncthreads();                            // drains DMA; publishes buf0

    int cur = 0;
    for (int s = slo; s < shi; ++s, cur ^= 1) {
        const bool pf = (s + 1 < shi);
        float4 xa0, xa1, xb0, xb1;
        int nci0 = 0;
        if (pf) {
            const int sl = s + 1;
            const int h2 = h + (sl >> 3) - 1;
            nci0 = (sl & 7) << 5;
            const size_t rowbase = (size_t)(b * 128 + h2) * 128;
            const float* ga = x + (rowbase + mA)      * 256 + nci0 + koff;
            const float* gb = x + (rowbase + mA + 64) * 256 + nci0 + koff;
            xa0 = *(const float4*)ga; xa1 = *(const float4*)(ga + 4);
            xb0 = *(const float4*)gb; xb1 = *(const float4*)(gb + 4);
            stage_kf(sl, cur ^ 1);              // DMA after x: x waits = vmcnt(6)
        }

        // ---- compute current slice: 3 taps x 4x4 tiles ----
#pragma unroll
        for (int tp = 0; tp < 3; ++tp) {        // dw=tp-1; pixel m reads row m+tp
            short8 af[4], bfr[4];
#pragma unroll
            for (int j = 0; j < 4; ++j)         // wave-contiguous 1 KB ds_read
                bfr[j] = *(const short8*)&KfB[cur][((tp << 3) + wjl + j) * 512
                                                   + lane * 8];
#pragma unroll
            for (int i = 0; i < 4; ++i)
                af[i] = *(const short8*)&Xs[cur][(wr + i * 16 + l15 + tp) * PXS
                                                 + lk * 8];
#pragma unroll
            for (int i = 0; i < 4; ++i)
#pragma unroll
                for (int j = 0; j < 4; ++j)
                    acc[i][j] = __builtin_amdgcn_mfma_f32_16x16x32_bf16(
                        af[i], bfr[j], acc[i][j], 0, 0, 0);
        }

        // ---- modulate + write next buffer (x landed under the MFMAs) ----
        if (pf) {
            float4 s0 = *(const float4*)&Ss[nci0 + koff];
            float4 s1 = *(const float4*)&Ss[nci0 + koff + 4];
            short8 ma, mb;
#pragma unroll
            for (int jj = 0; jj < 4; ++jj) {
                ma[jj]     = f2bf((&xa0.x)[jj] * (&s0.x)[jj]);
                ma[jj + 4] = f2bf((&xa1.x)[jj] * (&s1.x)[jj]);
                mb[jj]     = f2bf((&xb0.x)[jj] * (&s0.x)[jj]);
                mb[jj + 4] = f2bf((&xb1.x)[jj] * (&s1.x)[jj]);
            }
            *(short8*)&Xs[cur ^ 1][(mA + 1)  * PXS + koff] = ma;
            *(short8*)&Xs[cur ^ 1][(mA + 65) * PXS + koff] = mb;
        }
        __syncthreads();        // drains next-slice DMA; publishes Xs[cur^1]
    }

    // ---- epilogue: demod scale + f32 store (C/D: col=lane&15, row=(lane>>4)*4+r)
    float dj[4];
#pragma unroll
    for (int j = 0; j < 4; ++j) dj[j] = Ds[wc + j * 16 + l15];
    const size_t obase = (size_t)(b * 128 + h) * 128 * 256 + n0;
#pragma unroll
    for (int i = 0; i < 4; ++i) {
#pragma unroll
        for (int j = 0; j < 4; ++j) {
            const int n = wc + j * 16 + l15;
#pragma unroll
            for (int r = 0; r < 4; ++r) {
                const int m = wr + i * 16 + lk * 4 + r;
                out[obase + (size_t)m * 256 + n] = acc[i][j][r] * dj[j];
            }
        }
    }
}

extern "C" void kernel_launch(void* const* d_in, const int* in_sizes, int n_in,
                              void* d_out, int out_size, void* d_ws, size_t ws_size,
                              hipStream_t stream)
{
    const float* x     = (const float*)d_in[0];
    const float* style = (const float*)d_in[1];
    const float* kern  = (const float*)d_in[2];
    float* out = (float*)d_out;

    char*  ws    = (char*)d_ws;
    float* demod = (float*)ws;                           // 2048 f32   (8 KB)
    float* K2    = (float*)(ws + 8192);                  // 65536 f32  (256 KB)
    __hip_bfloat16* kT = (__hip_bfloat16*)(ws + 270336); // 589824 bf16 (1.18 MB)

    prep_k2   <<<256, 256, 0, stream>>>(kern, K2);
    prep_demod<<<8,   256, 0, stream>>>(style, K2, demod);
    prep_kf   <<<72,  256, 0, stream>>>(kern, kT);
    conv_mfma <<<2048, 256, 0, stream>>>(x, kT, style, demod, out);
}